// Round 4
// baseline (17386.110 us; speedup 1.0000x reference)
//
#include <hip/hip_runtime.h>
#include <hip/hip_bf16.h>
#include <math.h>

#define T_STEPS 1024
#define HDIM    2048
#define ADIM    64
#define NBLK    256
#define NTHR    1024          // 16 waves/block, 1 block/CU
#define ROWS_PB 8             // rows per block; wave pair (w, w+8) splits K

__device__ __forceinline__ float elu_f(float x)      { return x > 0.f ? x : expm1f(x); }
__device__ __forceinline__ float sigmoid_f(float x)  { return 1.f / (1.f + expf(-x)); }
__device__ __forceinline__ float softplus_f(float x) { return x > 0.f ? x + log1pf(expf(-x)) : log1pf(expf(x)); }

// Device-coherent relaxed 8B atomics: tag (hi32) + payload (lo32) publish in
// one store -> no fences, no vmcnt drains, no separate flags.
__device__ __forceinline__ unsigned long long cload64(const unsigned long long* p) {
    return __hip_atomic_load(p, __ATOMIC_RELAXED, __HIP_MEMORY_SCOPE_AGENT);
}
__device__ __forceinline__ void cstore64(unsigned long long* p, unsigned long long v) {
    __hip_atomic_store(p, v, __ATOMIC_RELAXED, __HIP_MEMORY_SCOPE_AGENT);
}
__device__ __forceinline__ unsigned long long pack_tag(unsigned tag, float v) {
    return ((unsigned long long)tag << 32) | (unsigned long long)__float_as_uint(v);
}

// Poll all 2048 tagged slots for `tag`; stash payloads into LDS.
// 1024 threads x 2 slots. Ends with __syncthreads (LDS fully staged).
__device__ __forceinline__ void consume_vec(const unsigned long long* __restrict__ tg,
                                            unsigned tag, float* __restrict__ lsv) {
    const int i = threadIdx.x;
    unsigned pend = 3u;
    while (pend) {
        if (pend & 1u) {
            const unsigned long long x = cload64(tg + i);
            if ((unsigned)(x >> 32) == tag) { lsv[i] = __uint_as_float((unsigned)x); pend &= ~1u; }
        }
        if (pend & 2u) {
            const unsigned long long x = cload64(tg + i + 1024);
            if ((unsigned)(x >> 32) == tag) { lsv[i + 1024] = __uint_as_float((unsigned)x); pend &= ~2u; }
        }
    }
    __syncthreads();
}

#define KEEP4(v) asm volatile("" : "+v"(v.x), "+v"(v.y), "+v"(v.z), "+v"(v.w))

// ---------------------------------------------------------------------------
// Persistent sequential kernel, K-split wave pairs. Wave w(&7) of a block owns
// row j = blk*8 + (w&7); lower wave (w<8) does k in [0,1024), upper wave does
// k in [1024,2048). Per-wave weights = 80 VGPRs -> fits the 128-VGPR cap at
// 16 waves/CU, so the whole 80MB weight set is register-resident device-wide.
// ---------------------------------------------------------------------------
__global__ void __launch_bounds__(NTHR, 4) gru_seq_kernel(
    const float* __restrict__ actions, const float* __restrict__ state,
    const float* __restrict__ W_ih, const float* __restrict__ W_hh,
    const float* __restrict__ b_ih, const float* __restrict__ b_hh,
    const float* __restrict__ fc1_w, const float* __restrict__ fc1_b,
    const float* __restrict__ fc2_w, const float* __restrict__ fc2_b,
    float* __restrict__ s_all,
    unsigned long long* __restrict__ tg0,
    unsigned long long* __restrict__ tg1,
    unsigned long long* __restrict__ tg2)
{
    __shared__ float lsv[HDIM];
    __shared__ float partU[ROWS_PB][3];   // upper-wave partials per row

    const int lane  = threadIdx.x & 63;
    const int wave  = threadIdx.x >> 6;        // 0..15
    const bool lower = (wave < ROWS_PB);
    const int w8    = wave & (ROWS_PB - 1);
    const int j     = blockIdx.x * ROWS_PB + w8;   // 0..2047
    const int c4    = lower ? 0 : 256;             // float4 offset of this wave's K-half

    // --- prologue: weight halves -> registers (4 float4 per vector) ---
    float4 wr[4], wz[4], wn[4], f1[4], f2[4];
    {
        const int kbase = lower ? 0 : 1024;
        const float4* p0 = (const float4*)(W_hh + (size_t)j * HDIM + kbase);
        const float4* p1 = (const float4*)(W_hh + (size_t)(HDIM + j) * HDIM + kbase);
        const float4* p2 = (const float4*)(W_hh + (size_t)(2 * HDIM + j) * HDIM + kbase);
        const float4* p3 = (const float4*)(fc1_w + (size_t)j * HDIM + kbase);
        const float4* p4 = (const float4*)(fc2_w + (size_t)j * HDIM + kbase);
        #pragma unroll
        for (int i = 0; i < 4; ++i) {
            wr[i] = p0[i * 64 + lane]; KEEP4(wr[i]);
            wz[i] = p1[i * 64 + lane]; KEEP4(wz[i]);
            wn[i] = p2[i * 64 + lane]; KEEP4(wn[i]);
            f1[i] = p3[i * 64 + lane]; KEEP4(f1[i]);
            f2[i] = p4[i * 64 + lane]; KEEP4(f2[i]);
        }
    }
    // gi row + biases: only the lower wave needs them
    const float wih_r = lower ? W_ih[(size_t)j * ADIM + lane] : 0.f;
    const float wih_z = lower ? W_ih[(size_t)(HDIM + j) * ADIM + lane] : 0.f;
    const float wih_n = lower ? W_ih[(size_t)(2 * HDIM + j) * ADIM + lane] : 0.f;
    const float bias_r = lower ? (b_ih[j] + b_hh[j]) : 0.f;
    const float bias_z = lower ? (b_ih[HDIM + j] + b_hh[HDIM + j]) : 0.f;
    const float bihn   = lower ? b_ih[2 * HDIM + j] : 0.f;
    const float bhhn   = lower ? b_hh[2 * HDIM + j] : 0.f;
    const float fb1    = lower ? fc1_b[j] : 0.f;
    const float fb2    = lower ? fc2_b[j] : 0.f;

    const float4* ls4 = (const float4*)lsv;

    for (int t = 0; t < T_STEPS; ++t) {
        const unsigned base = 3u * (unsigned)t;

        // ================= stage 1: GRU cell =================
        if (t == 0) {
            lsv[threadIdx.x]        = state[threadIdx.x];
            lsv[threadIdx.x + 1024] = state[threadIdx.x + 1024];
            __syncthreads();
        } else {
            consume_vec(tg2, base, lsv);            // s_{t-1}
        }
        const float hp = lsv[j];                     // hoisted: needed only by lower lane0
        {
            float dr = 0.f, dz = 0.f, dnH = 0.f;
            #pragma unroll
            for (int i = 0; i < 4; ++i) {
                const float4 s4 = ls4[c4 + i * 64 + lane];
                dr  += s4.x * wr[i].x + s4.y * wr[i].y + s4.z * wr[i].z + s4.w * wr[i].w;
                dz  += s4.x * wz[i].x + s4.y * wz[i].y + s4.z * wz[i].z + s4.w * wz[i].w;
                dnH += s4.x * wn[i].x + s4.y * wn[i].y + s4.z * wn[i].z + s4.w * wn[i].w;
            }
            float dnA = 0.f;
            if (lower) {
                const float av = actions[t * ADIM + lane];
                dr += av * wih_r;
                dz += av * wih_z;
                dnA = av * wih_n;
            }
            #pragma unroll
            for (int m = 32; m > 0; m >>= 1) {
                dr  += __shfl_xor(dr, m, 64);
                dz  += __shfl_xor(dz, m, 64);
                dnH += __shfl_xor(dnH, m, 64);
                dnA += __shfl_xor(dnA, m, 64);
            }
            if (!lower && lane == 0) {
                partU[w8][0] = dr; partU[w8][1] = dz; partU[w8][2] = dnH;
            }
            __syncthreads();
            if (lower && lane == 0) {
                const float drT  = dr  + partU[w8][0];
                const float dzT  = dz  + partU[w8][1];
                const float dnHT = dnH + partU[w8][2];
                const float r  = sigmoid_f(drT + bias_r);
                const float z  = sigmoid_f(dzT + bias_z);
                const float n  = tanhf(dnA + bihn + r * (dnHT + bhhn));
                const float hn = (1.f - z) * n + z * hp;
                cstore64(&tg0[j], pack_tag(base + 1u, elu_f(hn)));
            }
        }

        // ================= stage 2: fc1 =================
        consume_vec(tg0, base + 1u, lsv);
        {
            float d1 = 0.f;
            #pragma unroll
            for (int i = 0; i < 4; ++i) {
                const float4 s4 = ls4[c4 + i * 64 + lane];
                d1 += s4.x * f1[i].x + s4.y * f1[i].y + s4.z * f1[i].z + s4.w * f1[i].w;
            }
            #pragma unroll
            for (int m = 32; m > 0; m >>= 1) d1 += __shfl_xor(d1, m, 64);
            if (!lower && lane == 0) partU[w8][0] = d1;   // safe: stage-1 combiner done (it published tg0)
            __syncthreads();
            if (lower && lane == 0)
                cstore64(&tg1[j], pack_tag(base + 2u, elu_f(d1 + partU[w8][0] + fb1)));
        }

        // ================= stage 3: fc2 -> s_t =================
        consume_vec(tg1, base + 2u, lsv);
        {
            float d2 = 0.f;
            #pragma unroll
            for (int i = 0; i < 4; ++i) {
                const float4 s4 = ls4[c4 + i * 64 + lane];
                d2 += s4.x * f2[i].x + s4.y * f2[i].y + s4.z * f2[i].z + s4.w * f2[i].w;
            }
            #pragma unroll
            for (int m = 32; m > 0; m >>= 1) d2 += __shfl_xor(d2, m, 64);
            if (!lower && lane == 0) partU[w8][0] = d2;
            __syncthreads();
            if (lower && lane == 0) {
                const float v = elu_f(d2 + partU[w8][0] + fb2);
                cstore64(&tg2[j], pack_tag(base + 3u, v));
                s_all[(size_t)t * HDIM + j] = v;
            }
        }
    }
}

// ---------------------------------------------------------------------------
// Head GEMM (unchanged): C[t, n], n<2048 -> mean, else softplus(std).
// ---------------------------------------------------------------------------
__global__ void __launch_bounds__(256) head_gemm_kernel(
    const float* __restrict__ s_all,
    const float* __restrict__ mean_w, const float* __restrict__ mean_b,
    const float* __restrict__ std_w,  const float* __restrict__ std_b,
    float* __restrict__ out)
{
    __shared__ float As[32 * 64];
    __shared__ float Bs[32 * 64];

    const int n0 = blockIdx.x * 64;
    const int t0 = blockIdx.y * 64;
    const bool is_std = (n0 >= HDIM);
    const float* W    = is_std ? std_w : mean_w;
    const float* bias = is_std ? std_b : mean_b;
    const int j0 = is_std ? (n0 - HDIM) : n0;

    const int tid = threadIdx.x;
    const int tx = tid & 15;
    const int ty = tid >> 4;

    float acc[4][4] = {};

    for (int k0 = 0; k0 < HDIM; k0 += 32) {
        __syncthreads();
        #pragma unroll
        for (int p = 0; p < 2; ++p) {
            const int id = tid + p * 256;
            const int m  = id >> 3;
            const int kk = id & 7;
            const float4 a = *(const float4*)&s_all[(size_t)(t0 + m) * HDIM + k0 + kk * 4];
            As[(kk * 4 + 0) * 64 + m] = a.x;
            As[(kk * 4 + 1) * 64 + m] = a.y;
            As[(kk * 4 + 2) * 64 + m] = a.z;
            As[(kk * 4 + 3) * 64 + m] = a.w;
            const float4 b = *(const float4*)&W[(size_t)(j0 + m) * HDIM + k0 + kk * 4];
            Bs[(kk * 4 + 0) * 64 + m] = b.x;
            Bs[(kk * 4 + 1) * 64 + m] = b.y;
            Bs[(kk * 4 + 2) * 64 + m] = b.z;
            Bs[(kk * 4 + 3) * 64 + m] = b.w;
        }
        __syncthreads();

        #pragma unroll
        for (int k = 0; k < 32; ++k) {
            const float4 a = *(const float4*)&As[k * 64 + ty * 4];
            const float4 b = *(const float4*)&Bs[k * 64 + tx * 4];
            const float am[4] = {a.x, a.y, a.z, a.w};
            const float bn[4] = {b.x, b.y, b.z, b.w};
            #pragma unroll
            for (int i = 0; i < 4; ++i)
                #pragma unroll
                for (int jj = 0; jj < 4; ++jj)
                    acc[i][jj] += am[i] * bn[jj];
        }
    }

    const size_t off = is_std ? (size_t)T_STEPS * HDIM : 0;
    #pragma unroll
    for (int i = 0; i < 4; ++i) {
        const int tt = t0 + ty * 4 + i;
        const int jc = j0 + tx * 4;
        float4 v;
        float* vp = (float*)&v;
        #pragma unroll
        for (int jj = 0; jj < 4; ++jj) {
            float val = acc[i][jj] + bias[jc + jj];
            if (is_std) val = softplus_f(val);
            vp[jj] = val;
        }
        *(float4*)&out[off + (size_t)tt * HDIM + jc] = v;
    }
}

// ---------------------------------------------------------------------------
extern "C" void kernel_launch(void* const* d_in, const int* in_sizes, int n_in,
                              void* d_out, int out_size, void* d_ws, size_t ws_size,
                              hipStream_t stream) {
    (void)in_sizes; (void)n_in; (void)out_size; (void)ws_size;
    const float* actions = (const float*)d_in[0];
    const float* state   = (const float*)d_in[1];
    const float* W_ih    = (const float*)d_in[2];
    const float* W_hh    = (const float*)d_in[3];
    const float* b_ih    = (const float*)d_in[4];
    const float* b_hh    = (const float*)d_in[5];
    const float* fc1_w   = (const float*)d_in[6];
    const float* fc1_b   = (const float*)d_in[7];
    const float* fc2_w   = (const float*)d_in[8];
    const float* fc2_b   = (const float*)d_in[9];
    const float* mean_w  = (const float*)d_in[10];
    const float* mean_b  = (const float*)d_in[11];
    const float* std_w   = (const float*)d_in[12];
    const float* std_b   = (const float*)d_in[13];
    float* out = (float*)d_out;

    float* s_all = (float*)d_ws;                              // [T, H] fp32
    unsigned long long* tg0 = (unsigned long long*)(s_all + (size_t)T_STEPS * HDIM);
    unsigned long long* tg1 = tg0 + HDIM;
    unsigned long long* tg2 = tg1 + HDIM;
    // no memset needed: 0xAA poison never matches a ticket (1..3072)

    void* args[] = { &actions, &state, &W_ih, &W_hh, &b_ih, &b_hh,
                     &fc1_w, &fc1_b, &fc2_w, &fc2_b,
                     &s_all, &tg0, &tg1, &tg2 };
    hipLaunchCooperativeKernel((const void*)gru_seq_kernel,
                               dim3(NBLK), dim3(NTHR), args, 0, stream);

    dim3 grid(4096 / 64, T_STEPS / 64);
    head_gemm_kernel<<<grid, 256, 0, stream>>>(s_all, mean_w, mean_b, std_w, std_b, out);
}

// Round 5
// 11131.082 us; speedup vs baseline: 1.5619x; 1.5619x over previous
//
#include <hip/hip_runtime.h>
#include <hip/hip_bf16.h>
#include <math.h>

#define T_STEPS 1024
#define HDIM    2048
#define ADIM    64
#define NBLK    256
#define NTHR    512
#define WPB     (NTHR / 64)   // 8 waves/block -> 2048 waves = one per output row

__device__ __forceinline__ float elu_f(float x)      { return x > 0.f ? x : expm1f(x); }
__device__ __forceinline__ float sigmoid_f(float x)  { return 1.f / (1.f + expf(-x)); }
__device__ __forceinline__ float softplus_f(float x) { return x > 0.f ? x + log1pf(expf(-x)) : log1pf(expf(x)); }

// Device-coherent relaxed 8B atomics: tag (hi32) + payload (lo32) publish in
// one store -> no fences, no vmcnt drains, no separate flags.
__device__ __forceinline__ unsigned long long cload64(const unsigned long long* p) {
    return __hip_atomic_load(p, __ATOMIC_RELAXED, __HIP_MEMORY_SCOPE_AGENT);
}
__device__ __forceinline__ void cstore64(unsigned long long* p, unsigned long long v) {
    __hip_atomic_store(p, v, __ATOMIC_RELAXED, __HIP_MEMORY_SCOPE_AGENT);
}
__device__ __forceinline__ unsigned long long pack_tag(unsigned tag, float v) {
    return ((unsigned long long)tag << 32) | (unsigned long long)__float_as_uint(v);
}

// Poll all 2048 tagged slots for `tag`; stash payloads into LDS.
// 512 threads x 4 slots. Ends with __syncthreads (LDS fully staged).
__device__ __forceinline__ void consume_vec(const unsigned long long* __restrict__ tg,
                                            unsigned tag, float* __restrict__ lsv) {
    const int i = threadIdx.x;
    unsigned pend = 0xFu;
    while (pend) {
        #pragma unroll
        for (int q = 0; q < 4; ++q) {
            if (pend & (1u << q)) {
                const unsigned long long x = cload64(tg + i + q * NTHR);
                if ((unsigned)(x >> 32) == tag) {
                    lsv[i + q * NTHR] = __uint_as_float((unsigned)x);
                    pend &= ~(1u << q);
                }
            }
        }
    }
    __syncthreads();
}

// ---- explicit AGPR weight cache -------------------------------------------
// "a" register-class constraints force the values into AGPRs; the arch-VGPR
// allocator never sees a 160-wide live range, so it has nothing to spill.
// Reads are volatile so LICM cannot hoist them back into VGPR live ranges.
__device__ __forceinline__ void awrite4(float& a0, float& a1, float& a2, float& a3,
                                        const float4 v) {
    asm volatile("v_accvgpr_write_b32 %0, %4\n\t"
                 "v_accvgpr_write_b32 %1, %5\n\t"
                 "v_accvgpr_write_b32 %2, %6\n\t"
                 "v_accvgpr_write_b32 %3, %7"
                 : "=a"(a0), "=a"(a1), "=a"(a2), "=a"(a3)
                 : "v"(v.x), "v"(v.y), "v"(v.z), "v"(v.w));
}
__device__ __forceinline__ float4 aread4(const float a0, const float a1,
                                         const float a2, const float a3) {
    float4 r;
    asm volatile("v_accvgpr_read_b32 %0, %4\n\t"
                 "v_accvgpr_read_b32 %1, %5\n\t"
                 "v_accvgpr_read_b32 %2, %6\n\t"
                 "v_accvgpr_read_b32 %3, %7"
                 : "=v"(r.x), "=v"(r.y), "=v"(r.z), "=v"(r.w)
                 : "a"(a0), "a"(a1), "a"(a2), "a"(a3));
    return r;
}

// ---------------------------------------------------------------------------
// Persistent sequential kernel (R3 shape). Wave j holds its 5 weight rows
// (3x W_hh, fc1, fc2 = 160 floats/lane) in AGPRs. Per stage: poll tagged
// u64s -> LDS, dot AGPR weights vs LDS vector, wave-reduce, lane0 publishes.
// ---------------------------------------------------------------------------
__global__ void __launch_bounds__(NTHR, 1) gru_seq_kernel(
    const float* __restrict__ actions, const float* __restrict__ state,
    const float* __restrict__ W_ih, const float* __restrict__ W_hh,
    const float* __restrict__ b_ih, const float* __restrict__ b_hh,
    const float* __restrict__ fc1_w, const float* __restrict__ fc1_b,
    const float* __restrict__ fc2_w, const float* __restrict__ fc2_b,
    float* __restrict__ s_all,
    unsigned long long* __restrict__ tg0,
    unsigned long long* __restrict__ tg1,
    unsigned long long* __restrict__ tg2)
{
    __shared__ float lsv[HDIM];
    const int lane = threadIdx.x & 63;
    const int wave = threadIdx.x >> 6;
    const int j    = blockIdx.x * WPB + wave;   // 0..2047

    // AGPR backing store: ar[g*32 + i*4 + c], g in {wr,wz,wn,f1,f2}
    float ar[160];

    // --- prologue: weights -> AGPRs ---
    {
        const float4* p0 = (const float4*)(W_hh + (size_t)j * HDIM);
        const float4* p1 = (const float4*)(W_hh + (size_t)(HDIM + j) * HDIM);
        const float4* p2 = (const float4*)(W_hh + (size_t)(2 * HDIM + j) * HDIM);
        const float4* p3 = (const float4*)(fc1_w + (size_t)j * HDIM);
        const float4* p4 = (const float4*)(fc2_w + (size_t)j * HDIM);
        #pragma unroll
        for (int i = 0; i < 8; ++i) {
            awrite4(ar[  0 + i*4], ar[  1 + i*4], ar[  2 + i*4], ar[  3 + i*4], p0[i * 64 + lane]);
            awrite4(ar[ 32 + i*4], ar[ 33 + i*4], ar[ 34 + i*4], ar[ 35 + i*4], p1[i * 64 + lane]);
            awrite4(ar[ 64 + i*4], ar[ 65 + i*4], ar[ 66 + i*4], ar[ 67 + i*4], p2[i * 64 + lane]);
            awrite4(ar[ 96 + i*4], ar[ 97 + i*4], ar[ 98 + i*4], ar[ 99 + i*4], p3[i * 64 + lane]);
            awrite4(ar[128 + i*4], ar[129 + i*4], ar[130 + i*4], ar[131 + i*4], p4[i * 64 + lane]);
        }
    }
    const float wih_r = W_ih[(size_t)j * ADIM + lane];
    const float wih_z = W_ih[(size_t)(HDIM + j) * ADIM + lane];
    const float wih_n = W_ih[(size_t)(2 * HDIM + j) * ADIM + lane];
    const float bias_r = b_ih[j] + b_hh[j];
    const float bias_z = b_ih[HDIM + j] + b_hh[HDIM + j];
    const float bihn   = b_ih[2 * HDIM + j];
    const float bhhn   = b_hh[2 * HDIM + j];
    const float fb1    = fc1_b[j];
    const float fb2    = fc2_b[j];

    const float4* ls4 = (const float4*)lsv;

    for (int t = 0; t < T_STEPS; ++t) {
        const unsigned base = 3u * (unsigned)t;

        // ================= stage 1: GRU cell =================
        const float av = actions[t * ADIM + lane];   // independent; overlaps the spin
        if (t == 0) {
            #pragma unroll
            for (int q = 0; q < 4; ++q)
                lsv[threadIdx.x + q * NTHR] = state[threadIdx.x + q * NTHR];
            __syncthreads();
        } else {
            consume_vec(tg2, base, lsv);             // s_{t-1} (tag 3t)
        }
        {
            float dr = 0.f, dz = 0.f, dnH = 0.f;
            #pragma unroll
            for (int i = 0; i < 8; ++i) {
                const float4 s4 = ls4[i * 64 + lane];
                const float4 w0 = aread4(ar[  0 + i*4], ar[  1 + i*4], ar[  2 + i*4], ar[  3 + i*4]);
                const float4 w1 = aread4(ar[ 32 + i*4], ar[ 33 + i*4], ar[ 34 + i*4], ar[ 35 + i*4]);
                const float4 w2 = aread4(ar[ 64 + i*4], ar[ 65 + i*4], ar[ 66 + i*4], ar[ 67 + i*4]);
                dr  += s4.x * w0.x + s4.y * w0.y + s4.z * w0.z + s4.w * w0.w;
                dz  += s4.x * w1.x + s4.y * w1.y + s4.z * w1.z + s4.w * w1.w;
                dnH += s4.x * w2.x + s4.y * w2.y + s4.z * w2.z + s4.w * w2.w;
            }
            float dnA = av * wih_n;
            dr += av * wih_r;
            dz += av * wih_z;
            #pragma unroll
            for (int m = 32; m > 0; m >>= 1) {
                dr  += __shfl_xor(dr, m, 64);
                dz  += __shfl_xor(dz, m, 64);
                dnH += __shfl_xor(dnH, m, 64);
                dnA += __shfl_xor(dnA, m, 64);
            }
            if (lane == 0) {
                const float r  = sigmoid_f(dr + bias_r);
                const float z  = sigmoid_f(dz + bias_z);
                const float n  = tanhf(dnA + bihn + r * (dnH + bhhn));
                const float hp = lsv[j];
                const float hn = (1.f - z) * n + z * hp;
                cstore64(&tg0[j], pack_tag(base + 1u, elu_f(hn)));
            }
        }
        __syncthreads();   // protect lsv before next consumer overwrites it

        // ================= stage 2: fc1 =================
        consume_vec(tg0, base + 1u, lsv);
        {
            float d1 = 0.f;
            #pragma unroll
            for (int i = 0; i < 8; ++i) {
                const float4 s4 = ls4[i * 64 + lane];
                const float4 w = aread4(ar[96 + i*4], ar[97 + i*4], ar[98 + i*4], ar[99 + i*4]);
                d1 += s4.x * w.x + s4.y * w.y + s4.z * w.z + s4.w * w.w;
            }
            #pragma unroll
            for (int m = 32; m > 0; m >>= 1) d1 += __shfl_xor(d1, m, 64);
            if (lane == 0) cstore64(&tg1[j], pack_tag(base + 2u, elu_f(d1 + fb1)));
        }
        __syncthreads();

        // ================= stage 3: fc2 -> s_t =================
        consume_vec(tg1, base + 2u, lsv);
        {
            float d2 = 0.f;
            #pragma unroll
            for (int i = 0; i < 8; ++i) {
                const float4 s4 = ls4[i * 64 + lane];
                const float4 w = aread4(ar[128 + i*4], ar[129 + i*4], ar[130 + i*4], ar[131 + i*4]);
                d2 += s4.x * w.x + s4.y * w.y + s4.z * w.z + s4.w * w.w;
            }
            #pragma unroll
            for (int m = 32; m > 0; m >>= 1) d2 += __shfl_xor(d2, m, 64);
            if (lane == 0) {
                const float v = elu_f(d2 + fb2);
                cstore64(&tg2[j], pack_tag(base + 3u, v));
                s_all[(size_t)t * HDIM + j] = v;   // plain store; head GEMM reads after kernel end
            }
        }
        __syncthreads();
    }
}

// ---------------------------------------------------------------------------
// Head GEMM (unchanged): C[t, n], n<2048 -> mean, else softplus(std).
// ---------------------------------------------------------------------------
__global__ void __launch_bounds__(256) head_gemm_kernel(
    const float* __restrict__ s_all,
    const float* __restrict__ mean_w, const float* __restrict__ mean_b,
    const float* __restrict__ std_w,  const float* __restrict__ std_b,
    float* __restrict__ out)
{
    __shared__ float As[32 * 64];
    __shared__ float Bs[32 * 64];

    const int n0 = blockIdx.x * 64;
    const int t0 = blockIdx.y * 64;
    const bool is_std = (n0 >= HDIM);
    const float* W    = is_std ? std_w : mean_w;
    const float* bias = is_std ? std_b : mean_b;
    const int j0 = is_std ? (n0 - HDIM) : n0;

    const int tid = threadIdx.x;
    const int tx = tid & 15;
    const int ty = tid >> 4;

    float acc[4][4] = {};

    for (int k0 = 0; k0 < HDIM; k0 += 32) {
        __syncthreads();
        #pragma unroll
        for (int p = 0; p < 2; ++p) {
            const int id = tid + p * 256;
            const int m  = id >> 3;
            const int kk = id & 7;
            const float4 a = *(const float4*)&s_all[(size_t)(t0 + m) * HDIM + k0 + kk * 4];
            As[(kk * 4 + 0) * 64 + m] = a.x;
            As[(kk * 4 + 1) * 64 + m] = a.y;
            As[(kk * 4 + 2) * 64 + m] = a.z;
            As[(kk * 4 + 3) * 64 + m] = a.w;
            const float4 b = *(const float4*)&W[(size_t)(j0 + m) * HDIM + k0 + kk * 4];
            Bs[(kk * 4 + 0) * 64 + m] = b.x;
            Bs[(kk * 4 + 1) * 64 + m] = b.y;
            Bs[(kk * 4 + 2) * 64 + m] = b.z;
            Bs[(kk * 4 + 3) * 64 + m] = b.w;
        }
        __syncthreads();

        #pragma unroll
        for (int k = 0; k < 32; ++k) {
            const float4 a = *(const float4*)&As[k * 64 + ty * 4];
            const float4 b = *(const float4*)&Bs[k * 64 + tx * 4];
            const float am[4] = {a.x, a.y, a.z, a.w};
            const float bn[4] = {b.x, b.y, b.z, b.w};
            #pragma unroll
            for (int i = 0; i < 4; ++i)
                #pragma unroll
                for (int jj = 0; jj < 4; ++jj)
                    acc[i][jj] += am[i] * bn[jj];
        }
    }

    const size_t off = is_std ? (size_t)T_STEPS * HDIM : 0;
    #pragma unroll
    for (int i = 0; i < 4; ++i) {
        const int tt = t0 + ty * 4 + i;
        const int jc = j0 + tx * 4;
        float4 v;
        float* vp = (float*)&v;
        #pragma unroll
        for (int jj = 0; jj < 4; ++jj) {
            float val = acc[i][jj] + bias[jc + jj];
            if (is_std) val = softplus_f(val);
            vp[jj] = val;
        }
        *(float4*)&out[off + (size_t)tt * HDIM + jc] = v;
    }
}

// ---------------------------------------------------------------------------
extern "C" void kernel_launch(void* const* d_in, const int* in_sizes, int n_in,
                              void* d_out, int out_size, void* d_ws, size_t ws_size,
                              hipStream_t stream) {
    (void)in_sizes; (void)n_in; (void)out_size; (void)ws_size;
    const float* actions = (const float*)d_in[0];
    const float* state   = (const float*)d_in[1];
    const float* W_ih    = (const float*)d_in[2];
    const float* W_hh    = (const float*)d_in[3];
    const float* b_ih    = (const float*)d_in[4];
    const float* b_hh    = (const float*)d_in[5];
    const float* fc1_w   = (const float*)d_in[6];
    const float* fc1_b   = (const float*)d_in[7];
    const float* fc2_w   = (const float*)d_in[8];
    const float* fc2_b   = (const float*)d_in[9];
    const float* mean_w  = (const float*)d_in[10];
    const float* mean_b  = (const float*)d_in[11];
    const float* std_w   = (const float*)d_in[12];
    const float* std_b   = (const float*)d_in[13];
    float* out = (float*)d_out;

    float* s_all = (float*)d_ws;                              // [T, H] fp32
    unsigned long long* tg0 = (unsigned long long*)(s_all + (size_t)T_STEPS * HDIM);
    unsigned long long* tg1 = tg0 + HDIM;
    unsigned long long* tg2 = tg1 + HDIM;
    // no memset needed: 0xAA poison never matches a ticket (1..3072)

    void* args[] = { &actions, &state, &W_ih, &W_hh, &b_ih, &b_hh,
                     &fc1_w, &fc1_b, &fc2_w, &fc2_b,
                     &s_all, &tg0, &tg1, &tg2 };
    hipLaunchCooperativeKernel((const void*)gru_seq_kernel,
                               dim3(NBLK), dim3(NTHR), args, 0, stream);

    dim3 grid(4096 / 64, T_STEPS / 64);
    head_gemm_kernel<<<grid, 256, 0, stream>>>(s_all, mean_w, mean_b, std_w, std_b, out);
}